// Round 10
// baseline (162.127 us; speedup 1.0000x reference)
//
#include <hip/hip_runtime.h>
#include <math.h>

#define B_ 2
#define S_ 2048
#define M_ 1024
#define R_ 64
#define N_ 16
#define NC 64          // s-chunks
#define CH 32          // S_/NC
#define LOG2E 1.44269504088896f

// ws float offsets
#define DT_OFF  0                    // 4,194,304
#define AGG_OFF 4194304              // 4,194,304  (g,h)x16n per (b,c,m)
#define BWT_OFF 8388608              // 16,384
#define CWT_OFF 8404992              // 16,384
#define PB_OFF  8421376              // 131,072 (2 k-split partials, B)
#define PC_OFF  8552448              // 131,072 (C)
// total 8,683,520 floats = 34.7 MiB

// ============================================================================
// dt = clip(softplus(delta @ Wdt^T + bdt), 1e-6, 10); grid (4, 512) x 256.
// Embeds the Bw/Cw transpose (8 elements per block; consumed by NEXT kernel).
// (R4-proven form.)
// ============================================================================
__global__ __launch_bounds__(256) void k_dt(const float* __restrict__ delta,
                                            const float* __restrict__ Wdt,
                                            const float* __restrict__ bdt,
                                            const float* __restrict__ Bw,
                                            const float* __restrict__ Cw,
                                            float* __restrict__ dt,
                                            float* __restrict__ BwT,
                                            float* __restrict__ CwT) {
    int bid = blockIdx.y * 4 + blockIdx.x;             // 0..2047
    if (threadIdx.x < 8) {
        int idx = bid * 8 + threadIdx.x;               // 0..16383
        int mt = idx >> 4, nt = idx & 15;
        BwT[idx] = Bw[nt * M_ + mt];
        CwT[idx] = Cw[nt * M_ + mt];
    }
    int m    = blockIdx.x * 256 + threadIdx.x;         // 0..1023
    int row0 = blockIdx.y * 8;                         // bs base
    float w[R_];
    const float4* W4 = reinterpret_cast<const float4*>(Wdt + (size_t)m * R_);
#pragma unroll
    for (int i = 0; i < R_ / 4; ++i) {
        float4 v = W4[i];
        w[4*i] = v.x; w[4*i+1] = v.y; w[4*i+2] = v.z; w[4*i+3] = v.w;
    }
    float bias = bdt[m];
#pragma unroll 1
    for (int r = 0; r < 8; ++r) {
        int bs = row0 + r;
        const float* dr = delta + (size_t)bs * R_;     // wave-uniform -> s_load
        float acc = bias;
#pragma unroll
        for (int k = 0; k < R_; ++k) acc = fmaf(dr[k], w[k], acc);
        float sp = fmaxf(acc, 0.f) + log1pf(expf(-fabsf(acc)));
        sp = fminf(fmaxf(sp, 1e-6f), 10.0f);
        dt[(size_t)bs * M_ + m] = sp;
    }
}

// ============================================================================
// B/C projection, 2-way K-split partials; grid (256 row-groups, 2 k-splits).
// Coalesced via BwT/CwT[k][n]. (R4-proven form.)
// ============================================================================
__global__ __launch_bounds__(256) void k_bc_partial(const float* __restrict__ u,
                                                    const float* __restrict__ BwT,
                                                    const float* __restrict__ CwT,
                                                    float* __restrict__ pB,
                                                    float* __restrict__ pC) {
    __shared__ float uLds[16 * 516];                   // padded: stride 516
    int r0 = blockIdx.x * 16;
    int k0 = blockIdx.y * 512;
    for (int i = threadIdx.x; i < 2048; i += 256) {
        int r = i >> 7, kq = i & 127;
        float4 v = *reinterpret_cast<const float4*>(&u[(size_t)(r0 + r) * M_ + k0 + kq * 4]);
        *reinterpret_cast<float4*>(&uLds[r * 516 + kq * 4]) = v;
    }
    __syncthreads();
    int r = threadIdx.x >> 4, n = threadIdx.x & 15;
    const float4* u4 = reinterpret_cast<const float4*>(uLds + r * 516);
    float accB = 0.f, accC = 0.f;
#pragma unroll 4
    for (int k4 = 0; k4 < 128; ++k4) {
        float4 uv = u4[k4];
        int kb = k0 + k4 * 4;
        accB = fmaf(uv.x, BwT[(kb+0)*16 + n], accB);
        accB = fmaf(uv.y, BwT[(kb+1)*16 + n], accB);
        accB = fmaf(uv.z, BwT[(kb+2)*16 + n], accB);
        accB = fmaf(uv.w, BwT[(kb+3)*16 + n], accB);
        accC = fmaf(uv.x, CwT[(kb+0)*16 + n], accC);
        accC = fmaf(uv.y, CwT[(kb+1)*16 + n], accC);
        accC = fmaf(uv.z, CwT[(kb+2)*16 + n], accC);
        accC = fmaf(uv.w, CwT[(kb+3)*16 + n], accC);
    }
    size_t o = (size_t)blockIdx.y * 65536 + (size_t)(r0 + r) * 16 + n;
    pB[o] = accB;
    pC[o] = accC;
}

// ============================================================================
// pass1: per-chunk (g = prod e^a, h) from (1,0), R4-proven recurrence form,
// exp2 pre-scaled. grid (16, NC, B_), 256 thr, 4 n/thread.
// Agg layout: Agg[((b*NC+c)*M_+m)*32 + n0*2 + 2j + {0:g,1:h}]
// ============================================================================
__global__ __launch_bounds__(256) void k_pass1(const float* __restrict__ dt,
                                               const float* __restrict__ u,
                                               const float* __restrict__ pB,
                                               const float* __restrict__ A_log,
                                               float* __restrict__ Agg) {
    __shared__ float ldsDt[CH * 64], ldsU[CH * 64], ldsB[CH * 16];
    const int m0 = blockIdx.x * 64, c = blockIdx.y, b = blockIdx.z;
    const int s0 = c * CH;
    const int tid = threadIdx.x;
    for (int i = tid; i < 512; i += 256) {             // float4 staging
        int s = i >> 4, mq = (i & 15) * 4;
        size_t off = ((size_t)(b * S_ + s0 + s)) * M_ + m0 + mq;
        *reinterpret_cast<float4*>(&ldsDt[s * 64 + mq]) = *reinterpret_cast<const float4*>(&dt[off]);
        *reinterpret_cast<float4*>(&ldsU [s * 64 + mq]) = *reinterpret_cast<const float4*>(&u[off]);
    }
    {
        size_t base = (size_t)(b * S_ + s0) * N_;
        for (int i = tid; i < CH * 16; i += 256)
            ldsB[i] = pB[base + i] + pB[65536 + base + i];
    }
    __syncthreads();
    const int lane = tid & 63, wave = tid >> 6;
    const int ml = wave * 16 + (lane & 15);
    const int m  = m0 + ml;
    const int n0 = (lane >> 4) * 4;
    float Aa2[4], h[4] = {0,0,0,0}, g[4] = {1.f,1.f,1.f,1.f};
#pragma unroll
    for (int j = 0; j < 4; ++j) {
        float a = -expf(A_log[(size_t)(n0 + j) * M_ + m]);
        Aa2[j] = fminf(fmaxf(a, -10.f), -1e-6f) * LOG2E;
    }
    for (int s = 0; s < CH; ++s) {
        float dtv = ldsDt[s * 64 + ml];
        float uv  = ldsU [s * 64 + ml];
        float du  = dtv * uv;
        float4 bv = *reinterpret_cast<const float4*>(&ldsB[s * 16 + n0]);
        float bb[4] = {bv.x, bv.y, bv.z, bv.w};
#pragma unroll
        for (int j = 0; j < 4; ++j) {
            float ea = exp2f(dtv * Aa2[j]);
            h[j] = fmaf(ea, h[j], g[j] * (du * bb[j]));
            g[j] *= ea;
        }
    }
    float* dst = Agg + ((size_t)(b * NC + c) * M_ + m) * 32 + n0 * 2;
    *reinterpret_cast<float4*>(dst)     = make_float4(g[0], h[0], g[1], h[1]);
    *reinterpret_cast<float4*>(dst + 4) = make_float4(g[2], h[2], g[3], h[3]);
}

// ============================================================================
// pass3: fold predecessor chunk aggs (4-batched, fixed ascending order ==
// validated pass2 arithmetic), then recurrence + y + out.
// grid (16, NC, B_), 256 thr, 4 n/thread.
// ============================================================================
__global__ __launch_bounds__(256) void k_pass3(const float* __restrict__ dt,
                                               const float* __restrict__ u,
                                               const float* __restrict__ pB,
                                               const float* __restrict__ pC,
                                               const float* __restrict__ A_log,
                                               const float* __restrict__ Dskip,
                                               const float* __restrict__ Agg,
                                               float* __restrict__ out) {
    __shared__ float ldsDt[CH * 64], ldsU[CH * 64], ldsB[CH * 16], ldsC[CH * 16];
    const int m0 = blockIdx.x * 64, c = blockIdx.y, b = blockIdx.z;
    const int s0 = c * CH;
    const int tid = threadIdx.x;
    for (int i = tid; i < 512; i += 256) {
        int s = i >> 4, mq = (i & 15) * 4;
        size_t off = ((size_t)(b * S_ + s0 + s)) * M_ + m0 + mq;
        *reinterpret_cast<float4*>(&ldsDt[s * 64 + mq]) = *reinterpret_cast<const float4*>(&dt[off]);
        *reinterpret_cast<float4*>(&ldsU [s * 64 + mq]) = *reinterpret_cast<const float4*>(&u[off]);
    }
    {
        size_t base = (size_t)(b * S_ + s0) * N_;
        for (int i = tid; i < CH * 16; i += 256) {
            ldsB[i] = pB[base + i] + pB[65536 + base + i];
            ldsC[i] = pC[base + i] + pC[65536 + base + i];
        }
    }
    const int lane = tid & 63, wave = tid >> 6;
    const int ml = wave * 16 + (lane & 15);
    const int m  = m0 + ml;
    const int ng = lane >> 4, n0 = ng * 4;

    // ---- exclusive fold over chunks 0..c-1 (same fma order as old pass2) ----
    float g[4] = {1.f,1.f,1.f,1.f}, h[4] = {0.f,0.f,0.f,0.f};
    {
        const float* aggB = Agg + ((size_t)(b * NC) * M_ + m) * 32 + n0 * 2;
        const size_t cstride = (size_t)M_ * 32;
        int cp = 0;
        for (; cp + 4 <= c; cp += 4) {
            float4 q[8];
#pragma unroll
            for (int t = 0; t < 4; ++t) {
                q[2*t]   = *reinterpret_cast<const float4*>(aggB + (size_t)(cp + t) * cstride);
                q[2*t+1] = *reinterpret_cast<const float4*>(aggB + (size_t)(cp + t) * cstride + 4);
            }
#pragma unroll
            for (int t = 0; t < 4; ++t) {
                float4 a0 = q[2*t], a1 = q[2*t+1];
                h[0] = fmaf(a0.x, h[0], g[0] * a0.y); g[0] *= a0.x;
                h[1] = fmaf(a0.z, h[1], g[1] * a0.w); g[1] *= a0.z;
                h[2] = fmaf(a1.x, h[2], g[2] * a1.y); g[2] *= a1.x;
                h[3] = fmaf(a1.z, h[3], g[3] * a1.w); g[3] *= a1.z;
            }
        }
        for (; cp < c; ++cp) {
            float4 a0 = *reinterpret_cast<const float4*>(aggB + (size_t)cp * cstride);
            float4 a1 = *reinterpret_cast<const float4*>(aggB + (size_t)cp * cstride + 4);
            h[0] = fmaf(a0.x, h[0], g[0] * a0.y); g[0] *= a0.x;
            h[1] = fmaf(a0.z, h[1], g[1] * a0.w); g[1] *= a0.z;
            h[2] = fmaf(a1.x, h[2], g[2] * a1.y); g[2] *= a1.x;
            h[3] = fmaf(a1.z, h[3], g[3] * a1.w); g[3] *= a1.z;
        }
    }
    float Aa2[4];
#pragma unroll
    for (int j = 0; j < 4; ++j) {
        float a = -expf(A_log[(size_t)(n0 + j) * M_ + m]);
        Aa2[j] = fminf(fmaxf(a, -10.f), -1e-6f) * LOG2E;
    }
    const float Dm = Dskip[m];
    __syncthreads();

    for (int s = 0; s < CH; ++s) {
        float dtv = ldsDt[s * 64 + ml];
        float uv  = ldsU [s * 64 + ml];
        float du  = dtv * uv;
        float4 bv = *reinterpret_cast<const float4*>(&ldsB[s * 16 + n0]);
        float4 cv = *reinterpret_cast<const float4*>(&ldsC[s * 16 + n0]);
        float bb[4] = {bv.x, bv.y, bv.z, bv.w};
        float cc[4] = {cv.x, cv.y, cv.z, cv.w};
        float y = 0.f;
#pragma unroll
        for (int j = 0; j < 4; ++j) {
            float ea = exp2f(dtv * Aa2[j]);
            h[j] = fmaf(ea, h[j], g[j] * (du * bb[j]));
            g[j] *= ea;
            y = fmaf(h[j], cc[j], y);
        }
        y += __shfl_xor(y, 16, 64);
        y += __shfl_xor(y, 32, 64);
        if (ng == 0) {
            float o = y + uv * Dm;
            o = fminf(fmaxf(o, -10000.f), 10000.f);
            out[((size_t)(b * S_ + s0 + s)) * M_ + m] = o;
        }
    }
}

extern "C" void kernel_launch(void* const* d_in, const int* in_sizes, int n_in,
                              void* d_out, int out_size, void* d_ws, size_t ws_size,
                              hipStream_t stream) {
    const float* u     = (const float*)d_in[0];
    const float* delta = (const float*)d_in[1];
    const float* Wdt   = (const float*)d_in[2];
    const float* bdt   = (const float*)d_in[3];
    const float* A_log = (const float*)d_in[4];
    const float* Dski  = (const float*)d_in[5];
    const float* Bw    = (const float*)d_in[6];
    const float* Cw    = (const float*)d_in[7];
    float* out = (float*)d_out;
    float* ws  = (float*)d_ws;

    float* dt  = ws + DT_OFF;
    float* Agg = ws + AGG_OFF;
    float* BwT = ws + BWT_OFF;
    float* CwT = ws + CWT_OFF;
    float* pB  = ws + PB_OFF;
    float* pC  = ws + PC_OFF;

    k_dt<<<dim3(4, 512), 256, 0, stream>>>(delta, Wdt, bdt, Bw, Cw, dt, BwT, CwT);
    k_bc_partial<<<dim3(256, 2), 256, 0, stream>>>(u, BwT, CwT, pB, pC);
    k_pass1<<<dim3(16, NC, B_), 256, 0, stream>>>(dt, u, pB, A_log, Agg);
    k_pass3<<<dim3(16, NC, B_), 256, 0, stream>>>(dt, u, pB, pC, A_log, Dski, Agg, out);
}

// Round 11
// 122.982 us; speedup vs baseline: 1.3183x; 1.3183x over previous
//
#include <hip/hip_runtime.h>
#include <math.h>

#define B_ 2
#define S_ 2048
#define M_ 1024
#define R_ 64
#define N_ 16
#define NC 32          // s-chunks
#define CH 64          // S_/NC
#define LOG2E 1.44269504088896f

// ws float offsets
#define DT_OFF  0                    // 4,194,304
#define AGG_OFF 4194304              // 2,097,152: [b*16+mt][c][tid][8]
#define PB_OFF  6291456              // 131,072 (2 k-split partials, B)
#define PC_OFF  6422528              // 131,072 (C)
// total 6,553,600 floats = 26.2 MiB

// ============================================================================
// k_front: blocks 0..511 = B/C projection (k-split 2), 512..2559 = dt GEMM.
// bc: u staged in LDS (R4-proven); weights read DIRECT from row-major Bw/Cw
//     with n = tid>>4 so each 16-lane group broadcasts one weight row (no
//     transpose, no gather). dt: W streamed in float4 panels (~40 VGPR, no
//     64-reg residency -> no spill, the R6 failure mode).
// ============================================================================
__global__ __launch_bounds__(256) void k_front(
    const float* __restrict__ u, const float* __restrict__ delta,
    const float* __restrict__ Wdt, const float* __restrict__ bdt,
    const float* __restrict__ Bw, const float* __restrict__ Cw,
    float* __restrict__ dt, float* __restrict__ pB, float* __restrict__ pC)
{
    __shared__ float uLds[16 * 516];                   // bc branch only (33 KB)
    const int bid = blockIdx.x;
    const int tid = threadIdx.x;

    if (bid < 512) {
        const int r0 = (bid >> 1) * 16;
        const int k0 = (bid & 1) * 512;
        for (int i = tid; i < 2048; i += 256) {
            int r = i >> 7, kq = i & 127;
            *reinterpret_cast<float4*>(&uLds[r * 516 + kq * 4]) =
                *reinterpret_cast<const float4*>(&u[(size_t)(r0 + r) * M_ + k0 + kq * 4]);
        }
        __syncthreads();
        const int n = tid >> 4, r = tid & 15;          // 16 lanes share n -> broadcast W
        const float4* u4  = reinterpret_cast<const float4*>(uLds + r * 516);
        const float4* wB4 = reinterpret_cast<const float4*>(Bw + (size_t)n * M_ + k0);
        const float4* wC4 = reinterpret_cast<const float4*>(Cw + (size_t)n * M_ + k0);
        float accB = 0.f, accC = 0.f;
#pragma unroll 4
        for (int k4 = 0; k4 < 128; ++k4) {
            float4 uv = u4[k4], wb = wB4[k4], wc = wC4[k4];
            accB = fmaf(uv.x, wb.x, accB);
            accB = fmaf(uv.y, wb.y, accB);
            accB = fmaf(uv.z, wb.z, accB);
            accB = fmaf(uv.w, wb.w, accB);
            accC = fmaf(uv.x, wc.x, accC);
            accC = fmaf(uv.y, wc.y, accC);
            accC = fmaf(uv.z, wc.z, accC);
            accC = fmaf(uv.w, wc.w, accC);
        }
        size_t o = (size_t)(bid & 1) * 65536 + (size_t)(r0 + r) * 16 + n;
        pB[o] = accB;
        pC[o] = accC;
    } else {
        const int bid2 = bid - 512;                    // 0..2047
        const int m    = (bid2 & 3) * 256 + tid;       // 0..1023
        const int row0 = (bid2 >> 2) * 8;              // bs base
        const float4* W4 = reinterpret_cast<const float4*>(Wdt + (size_t)m * R_);
        float bias = bdt[m];
        float acc[8];
#pragma unroll
        for (int r = 0; r < 8; ++r) acc[r] = bias;
#pragma unroll 4
        for (int kb = 0; kb < 16; ++kb) {              // stream W, 16B/panel
            float4 wv = W4[kb];
#pragma unroll
            for (int r = 0; r < 8; ++r) {
                float4 dv = *reinterpret_cast<const float4*>(
                    &delta[(size_t)(row0 + r) * R_ + kb * 4]);   // wave-uniform
                acc[r] = fmaf(dv.x, wv.x, acc[r]);
                acc[r] = fmaf(dv.y, wv.y, acc[r]);
                acc[r] = fmaf(dv.z, wv.z, acc[r]);
                acc[r] = fmaf(dv.w, wv.w, acc[r]);
            }
        }
#pragma unroll
        for (int r = 0; r < 8; ++r) {
            float sp = fmaxf(acc[r], 0.f) + log1pf(expf(-fabsf(acc[r])));
            sp = fminf(fmaxf(sp, 1e-6f), 10.0f);
            dt[(size_t)(row0 + r) * M_ + m] = sp;
        }
    }
}

// ============================================================================
// pass1: per-chunk (g = prod e^a, h) from (1,0); grid (16, NC, B_), 256 thr,
// 4 n/thread, CH=64. Agg layout [chain=(b*16+mt)][c][tid][8] -> fold reads
// are 2KB-contiguous per wave per chunk.
// ============================================================================
__global__ __launch_bounds__(256) void k_pass1(const float* __restrict__ dt,
                                               const float* __restrict__ u,
                                               const float* __restrict__ pB,
                                               const float* __restrict__ A_log,
                                               float* __restrict__ Agg) {
    __shared__ float ldsDt[CH * 64], ldsU[CH * 64], ldsB[CH * 16];
    const int m0 = blockIdx.x * 64, c = blockIdx.y, b = blockIdx.z;
    const int s0 = c * CH;
    const int tid = threadIdx.x;
    for (int i = tid; i < 1024; i += 256) {            // 64 rows x 16 float4
        int s = i >> 4, mq = (i & 15) * 4;
        size_t off = ((size_t)(b * S_ + s0 + s)) * M_ + m0 + mq;
        *reinterpret_cast<float4*>(&ldsDt[s * 64 + mq]) = *reinterpret_cast<const float4*>(&dt[off]);
        *reinterpret_cast<float4*>(&ldsU [s * 64 + mq]) = *reinterpret_cast<const float4*>(&u[off]);
    }
    {
        size_t base = (size_t)(b * S_ + s0) * N_;
        for (int i = tid; i < CH * 16; i += 256)
            ldsB[i] = pB[base + i] + pB[65536 + base + i];
    }
    __syncthreads();
    const int lane = tid & 63, wave = tid >> 6;
    const int ml = wave * 16 + (lane & 15);
    const int m  = m0 + ml;
    const int n0 = (lane >> 4) * 4;
    float Aa2[4], h[4] = {0,0,0,0}, g[4] = {1.f,1.f,1.f,1.f};
#pragma unroll
    for (int j = 0; j < 4; ++j) {
        float a = -expf(A_log[(size_t)(n0 + j) * M_ + m]);
        Aa2[j] = fminf(fmaxf(a, -10.f), -1e-6f) * LOG2E;
    }
    for (int s = 0; s < CH; ++s) {
        float dtv = ldsDt[s * 64 + ml];
        float uv  = ldsU [s * 64 + ml];
        float du  = dtv * uv;
        float4 bv = *reinterpret_cast<const float4*>(&ldsB[s * 16 + n0]);
        float bb[4] = {bv.x, bv.y, bv.z, bv.w};
#pragma unroll
        for (int j = 0; j < 4; ++j) {
            float ea = exp2f(dtv * Aa2[j]);
            h[j] = fmaf(ea, h[j], g[j] * (du * bb[j]));
            g[j] *= ea;
        }
    }
    float* dst = Agg + ((size_t)(b * 16 + blockIdx.x) * NC + c) * 2048 + tid * 8;
    *reinterpret_cast<float4*>(dst)     = make_float4(g[0], h[0], g[1], h[1]);
    *reinterpret_cast<float4*>(dst + 4) = make_float4(g[2], h[2], g[3], h[3]);
}

// ============================================================================
// pass3: fold predecessor chunk aggs (<=31, 4-batched, contiguous layout,
// fixed ascending order), then recurrence + y + out. grid (16, NC, B_).
// ============================================================================
__global__ __launch_bounds__(256) void k_pass3(const float* __restrict__ dt,
                                               const float* __restrict__ u,
                                               const float* __restrict__ pB,
                                               const float* __restrict__ pC,
                                               const float* __restrict__ A_log,
                                               const float* __restrict__ Dskip,
                                               const float* __restrict__ Agg,
                                               float* __restrict__ out) {
    __shared__ float ldsDt[CH * 64], ldsU[CH * 64], ldsB[CH * 16], ldsC[CH * 16];
    const int m0 = blockIdx.x * 64, c = blockIdx.y, b = blockIdx.z;
    const int s0 = c * CH;
    const int tid = threadIdx.x;
    for (int i = tid; i < 1024; i += 256) {
        int s = i >> 4, mq = (i & 15) * 4;
        size_t off = ((size_t)(b * S_ + s0 + s)) * M_ + m0 + mq;
        *reinterpret_cast<float4*>(&ldsDt[s * 64 + mq]) = *reinterpret_cast<const float4*>(&dt[off]);
        *reinterpret_cast<float4*>(&ldsU [s * 64 + mq]) = *reinterpret_cast<const float4*>(&u[off]);
    }
    {
        size_t base = (size_t)(b * S_ + s0) * N_;
        for (int i = tid; i < CH * 16; i += 256) {
            ldsB[i] = pB[base + i] + pB[65536 + base + i];
            ldsC[i] = pC[base + i] + pC[65536 + base + i];
        }
    }
    const int lane = tid & 63, wave = tid >> 6;
    const int ml = wave * 16 + (lane & 15);
    const int m  = m0 + ml;
    const int ng = lane >> 4, n0 = ng * 4;

    // ---- exclusive fold over chunks 0..c-1 (fixed order, contiguous reads) ----
    float g[4] = {1.f,1.f,1.f,1.f}, h[4] = {0.f,0.f,0.f,0.f};
    {
        const float* aggB = Agg + (size_t)(b * 16 + blockIdx.x) * NC * 2048 + tid * 8;
        int cp = 0;
        for (; cp + 4 <= c; cp += 4) {
            float4 q[8];
#pragma unroll
            for (int t = 0; t < 4; ++t) {
                q[2*t]   = *reinterpret_cast<const float4*>(aggB + (size_t)(cp + t) * 2048);
                q[2*t+1] = *reinterpret_cast<const float4*>(aggB + (size_t)(cp + t) * 2048 + 4);
            }
#pragma unroll
            for (int t = 0; t < 4; ++t) {
                float4 a0 = q[2*t], a1 = q[2*t+1];
                h[0] = fmaf(a0.x, h[0], g[0] * a0.y); g[0] *= a0.x;
                h[1] = fmaf(a0.z, h[1], g[1] * a0.w); g[1] *= a0.z;
                h[2] = fmaf(a1.x, h[2], g[2] * a1.y); g[2] *= a1.x;
                h[3] = fmaf(a1.z, h[3], g[3] * a1.w); g[3] *= a1.z;
            }
        }
        for (; cp < c; ++cp) {
            float4 a0 = *reinterpret_cast<const float4*>(aggB + (size_t)cp * 2048);
            float4 a1 = *reinterpret_cast<const float4*>(aggB + (size_t)cp * 2048 + 4);
            h[0] = fmaf(a0.x, h[0], g[0] * a0.y); g[0] *= a0.x;
            h[1] = fmaf(a0.z, h[1], g[1] * a0.w); g[1] *= a0.z;
            h[2] = fmaf(a1.x, h[2], g[2] * a1.y); g[2] *= a1.x;
            h[3] = fmaf(a1.z, h[3], g[3] * a1.w); g[3] *= a1.z;
        }
    }
    float Aa2[4];
#pragma unroll
    for (int j = 0; j < 4; ++j) {
        float a = -expf(A_log[(size_t)(n0 + j) * M_ + m]);
        Aa2[j] = fminf(fmaxf(a, -10.f), -1e-6f) * LOG2E;
    }
    const float Dm = Dskip[m];
    __syncthreads();

    for (int s = 0; s < CH; ++s) {
        float dtv = ldsDt[s * 64 + ml];
        float uv  = ldsU [s * 64 + ml];
        float du  = dtv * uv;
        float4 bv = *reinterpret_cast<const float4*>(&ldsB[s * 16 + n0]);
        float4 cv = *reinterpret_cast<const float4*>(&ldsC[s * 16 + n0]);
        float bb[4] = {bv.x, bv.y, bv.z, bv.w};
        float cc[4] = {cv.x, cv.y, cv.z, cv.w};
        float y = 0.f;
#pragma unroll
        for (int j = 0; j < 4; ++j) {
            float ea = exp2f(dtv * Aa2[j]);
            h[j] = fmaf(ea, h[j], g[j] * (du * bb[j]));
            g[j] *= ea;
            y = fmaf(h[j], cc[j], y);
        }
        y += __shfl_xor(y, 16, 64);
        y += __shfl_xor(y, 32, 64);
        if (ng == 0) {
            float o = y + uv * Dm;
            o = fminf(fmaxf(o, -10000.f), 10000.f);
            out[((size_t)(b * S_ + s0 + s)) * M_ + m] = o;
        }
    }
}

extern "C" void kernel_launch(void* const* d_in, const int* in_sizes, int n_in,
                              void* d_out, int out_size, void* d_ws, size_t ws_size,
                              hipStream_t stream) {
    const float* u     = (const float*)d_in[0];
    const float* delta = (const float*)d_in[1];
    const float* Wdt   = (const float*)d_in[2];
    const float* bdt   = (const float*)d_in[3];
    const float* A_log = (const float*)d_in[4];
    const float* Dski  = (const float*)d_in[5];
    const float* Bw    = (const float*)d_in[6];
    const float* Cw    = (const float*)d_in[7];
    float* out = (float*)d_out;
    float* ws  = (float*)d_ws;

    float* dt  = ws + DT_OFF;
    float* Agg = ws + AGG_OFF;
    float* pB  = ws + PB_OFF;
    float* pC  = ws + PC_OFF;

    k_front<<<2560, 256, 0, stream>>>(u, delta, Wdt, bdt, Bw, Cw, dt, pB, pC);
    k_pass1<<<dim3(16, NC, B_), 256, 0, stream>>>(dt, u, pB, A_log, Agg);
    k_pass3<<<dim3(16, NC, B_), 256, 0, stream>>>(dt, u, pB, pC, A_log, Dski, Agg, out);
}

// Round 12
// 117.691 us; speedup vs baseline: 1.3776x; 1.0450x over previous
//
#include <hip/hip_runtime.h>
#include <math.h>

#define B_ 2
#define S_ 2048
#define M_ 1024
#define R_ 64
#define N_ 16
#define NC 32          // s-chunks
#define CH 64          // S_/NC
#define LOG2E 1.44269504088896f

// ws float offsets
#define DT_OFF  0                    // 4,194,304
#define AGG_OFF 4194304              // 2,097,152: [b*16+mt][c][tid][8]
#define BWT_OFF 6291456              // 16,384
#define CWT_OFF 6307840              // 16,384
#define PB_OFF  6324224              // 131,072 (2 k-split partials, B)
#define PC_OFF  6455296              // 131,072 (C)
// total 6,586,368 floats = 26.3 MiB

// ============================================================================
// dt = clip(softplus(delta @ Wdt^T + bdt), 1e-6, 10); grid (4, 512) x 256.
// Embeds the Bw/Cw transpose (8 elements per block; consumed by NEXT kernel).
// R4-exact form: W row resident in 64 VGPRs, standalone kernel -> no spill.
// ============================================================================
__global__ __launch_bounds__(256) void k_dt(const float* __restrict__ delta,
                                            const float* __restrict__ Wdt,
                                            const float* __restrict__ bdt,
                                            const float* __restrict__ Bw,
                                            const float* __restrict__ Cw,
                                            float* __restrict__ dt,
                                            float* __restrict__ BwT,
                                            float* __restrict__ CwT) {
    int bid = blockIdx.y * 4 + blockIdx.x;             // 0..2047
    if (threadIdx.x < 8) {
        int idx = bid * 8 + threadIdx.x;               // 0..16383
        int mt = idx >> 4, nt = idx & 15;
        BwT[idx] = Bw[nt * M_ + mt];
        CwT[idx] = Cw[nt * M_ + mt];
    }
    int m    = blockIdx.x * 256 + threadIdx.x;         // 0..1023
    int row0 = blockIdx.y * 8;                         // bs base
    float w[R_];
    const float4* W4 = reinterpret_cast<const float4*>(Wdt + (size_t)m * R_);
#pragma unroll
    for (int i = 0; i < R_ / 4; ++i) {
        float4 v = W4[i];
        w[4*i] = v.x; w[4*i+1] = v.y; w[4*i+2] = v.z; w[4*i+3] = v.w;
    }
    float bias = bdt[m];
#pragma unroll 1
    for (int r = 0; r < 8; ++r) {
        int bs = row0 + r;
        const float* dr = delta + (size_t)bs * R_;     // wave-uniform -> s_load
        float acc = bias;
#pragma unroll
        for (int k = 0; k < R_; ++k) acc = fmaf(dr[k], w[k], acc);
        float sp = fmaxf(acc, 0.f) + log1pf(expf(-fabsf(acc)));
        sp = fminf(fmaxf(sp, 1e-6f), 10.0f);
        dt[(size_t)bs * M_ + m] = sp;
    }
}

// ============================================================================
// B/C projection, 2-way K-split partials; grid (256 row-groups, 2 k-splits).
// R4-exact form: coalesced via BwT/CwT[k][n].
// ============================================================================
__global__ __launch_bounds__(256) void k_bc_partial(const float* __restrict__ u,
                                                    const float* __restrict__ BwT,
                                                    const float* __restrict__ CwT,
                                                    float* __restrict__ pB,
                                                    float* __restrict__ pC) {
    __shared__ float uLds[16 * 516];                   // padded: stride 516
    int r0 = blockIdx.x * 16;
    int k0 = blockIdx.y * 512;
    for (int i = threadIdx.x; i < 2048; i += 256) {
        int r = i >> 7, kq = i & 127;
        float4 v = *reinterpret_cast<const float4*>(&u[(size_t)(r0 + r) * M_ + k0 + kq * 4]);
        *reinterpret_cast<float4*>(&uLds[r * 516 + kq * 4]) = v;
    }
    __syncthreads();
    int r = threadIdx.x >> 4, n = threadIdx.x & 15;
    const float4* u4 = reinterpret_cast<const float4*>(uLds + r * 516);
    float accB = 0.f, accC = 0.f;
#pragma unroll 4
    for (int k4 = 0; k4 < 128; ++k4) {
        float4 uv = u4[k4];
        int kb = k0 + k4 * 4;
        accB = fmaf(uv.x, BwT[(kb+0)*16 + n], accB);
        accB = fmaf(uv.y, BwT[(kb+1)*16 + n], accB);
        accB = fmaf(uv.z, BwT[(kb+2)*16 + n], accB);
        accB = fmaf(uv.w, BwT[(kb+3)*16 + n], accB);
        accC = fmaf(uv.x, CwT[(kb+0)*16 + n], accC);
        accC = fmaf(uv.y, CwT[(kb+1)*16 + n], accC);
        accC = fmaf(uv.z, CwT[(kb+2)*16 + n], accC);
        accC = fmaf(uv.w, CwT[(kb+3)*16 + n], accC);
    }
    size_t o = (size_t)blockIdx.y * 65536 + (size_t)(r0 + r) * 16 + n;
    pB[o] = accB;
    pC[o] = accC;
}

// ============================================================================
// pass1: per-chunk (g = prod e^a, h) from (1,0); grid (16, NC, B_), 256 thr,
// 4 n/thread, CH=64. Agg layout [chain=(b*16+mt)][c][tid][8] -> fold reads
// are 2KB-contiguous per wave per chunk. (R11-exact.)
// ============================================================================
__global__ __launch_bounds__(256) void k_pass1(const float* __restrict__ dt,
                                               const float* __restrict__ u,
                                               const float* __restrict__ pB,
                                               const float* __restrict__ A_log,
                                               float* __restrict__ Agg) {
    __shared__ float ldsDt[CH * 64], ldsU[CH * 64], ldsB[CH * 16];
    const int m0 = blockIdx.x * 64, c = blockIdx.y, b = blockIdx.z;
    const int s0 = c * CH;
    const int tid = threadIdx.x;
    for (int i = tid; i < 1024; i += 256) {            // 64 rows x 16 float4
        int s = i >> 4, mq = (i & 15) * 4;
        size_t off = ((size_t)(b * S_ + s0 + s)) * M_ + m0 + mq;
        *reinterpret_cast<float4*>(&ldsDt[s * 64 + mq]) = *reinterpret_cast<const float4*>(&dt[off]);
        *reinterpret_cast<float4*>(&ldsU [s * 64 + mq]) = *reinterpret_cast<const float4*>(&u[off]);
    }
    {
        size_t base = (size_t)(b * S_ + s0) * N_;
        for (int i = tid; i < CH * 16; i += 256)
            ldsB[i] = pB[base + i] + pB[65536 + base + i];
    }
    __syncthreads();
    const int lane = tid & 63, wave = tid >> 6;
    const int ml = wave * 16 + (lane & 15);
    const int m  = m0 + ml;
    const int n0 = (lane >> 4) * 4;
    float Aa2[4], h[4] = {0,0,0,0}, g[4] = {1.f,1.f,1.f,1.f};
#pragma unroll
    for (int j = 0; j < 4; ++j) {
        float a = -expf(A_log[(size_t)(n0 + j) * M_ + m]);
        Aa2[j] = fminf(fmaxf(a, -10.f), -1e-6f) * LOG2E;
    }
    for (int s = 0; s < CH; ++s) {
        float dtv = ldsDt[s * 64 + ml];
        float uv  = ldsU [s * 64 + ml];
        float du  = dtv * uv;
        float4 bv = *reinterpret_cast<const float4*>(&ldsB[s * 16 + n0]);
        float bb[4] = {bv.x, bv.y, bv.z, bv.w};
#pragma unroll
        for (int j = 0; j < 4; ++j) {
            float ea = exp2f(dtv * Aa2[j]);
            h[j] = fmaf(ea, h[j], g[j] * (du * bb[j]));
            g[j] *= ea;
        }
    }
    float* dst = Agg + ((size_t)(b * 16 + blockIdx.x) * NC + c) * 2048 + tid * 8;
    *reinterpret_cast<float4*>(dst)     = make_float4(g[0], h[0], g[1], h[1]);
    *reinterpret_cast<float4*>(dst + 4) = make_float4(g[2], h[2], g[3], h[3]);
}

// ============================================================================
// pass3: fold predecessor chunk aggs (<=31, 4-batched, contiguous layout,
// fixed ascending order), then recurrence + y + out. grid (16, NC, B_).
// (R11-exact.)
// ============================================================================
__global__ __launch_bounds__(256) void k_pass3(const float* __restrict__ dt,
                                               const float* __restrict__ u,
                                               const float* __restrict__ pB,
                                               const float* __restrict__ pC,
                                               const float* __restrict__ A_log,
                                               const float* __restrict__ Dskip,
                                               const float* __restrict__ Agg,
                                               float* __restrict__ out) {
    __shared__ float ldsDt[CH * 64], ldsU[CH * 64], ldsB[CH * 16], ldsC[CH * 16];
    const int m0 = blockIdx.x * 64, c = blockIdx.y, b = blockIdx.z;
    const int s0 = c * CH;
    const int tid = threadIdx.x;
    for (int i = tid; i < 1024; i += 256) {
        int s = i >> 4, mq = (i & 15) * 4;
        size_t off = ((size_t)(b * S_ + s0 + s)) * M_ + m0 + mq;
        *reinterpret_cast<float4*>(&ldsDt[s * 64 + mq]) = *reinterpret_cast<const float4*>(&dt[off]);
        *reinterpret_cast<float4*>(&ldsU [s * 64 + mq]) = *reinterpret_cast<const float4*>(&u[off]);
    }
    {
        size_t base = (size_t)(b * S_ + s0) * N_;
        for (int i = tid; i < CH * 16; i += 256) {
            ldsB[i] = pB[base + i] + pB[65536 + base + i];
            ldsC[i] = pC[base + i] + pC[65536 + base + i];
        }
    }
    const int lane = tid & 63, wave = tid >> 6;
    const int ml = wave * 16 + (lane & 15);
    const int m  = m0 + ml;
    const int ng = lane >> 4, n0 = ng * 4;

    // ---- exclusive fold over chunks 0..c-1 (fixed order, contiguous reads) ----
    float g[4] = {1.f,1.f,1.f,1.f}, h[4] = {0.f,0.f,0.f,0.f};
    {
        const float* aggB = Agg + (size_t)(b * 16 + blockIdx.x) * NC * 2048 + tid * 8;
        int cp = 0;
        for (; cp + 4 <= c; cp += 4) {
            float4 q[8];
#pragma unroll
            for (int t = 0; t < 4; ++t) {
                q[2*t]   = *reinterpret_cast<const float4*>(aggB + (size_t)(cp + t) * 2048);
                q[2*t+1] = *reinterpret_cast<const float4*>(aggB + (size_t)(cp + t) * 2048 + 4);
            }
#pragma unroll
            for (int t = 0; t < 4; ++t) {
                float4 a0 = q[2*t], a1 = q[2*t+1];
                h[0] = fmaf(a0.x, h[0], g[0] * a0.y); g[0] *= a0.x;
                h[1] = fmaf(a0.z, h[1], g[1] * a0.w); g[1] *= a0.z;
                h[2] = fmaf(a1.x, h[2], g[2] * a1.y); g[2] *= a1.x;
                h[3] = fmaf(a1.z, h[3], g[3] * a1.w); g[3] *= a1.z;
            }
        }
        for (; cp < c; ++cp) {
            float4 a0 = *reinterpret_cast<const float4*>(aggB + (size_t)cp * 2048);
            float4 a1 = *reinterpret_cast<const float4*>(aggB + (size_t)cp * 2048 + 4);
            h[0] = fmaf(a0.x, h[0], g[0] * a0.y); g[0] *= a0.x;
            h[1] = fmaf(a0.z, h[1], g[1] * a0.w); g[1] *= a0.z;
            h[2] = fmaf(a1.x, h[2], g[2] * a1.y); g[2] *= a1.x;
            h[3] = fmaf(a1.z, h[3], g[3] * a1.w); g[3] *= a1.z;
        }
    }
    float Aa2[4];
#pragma unroll
    for (int j = 0; j < 4; ++j) {
        float a = -expf(A_log[(size_t)(n0 + j) * M_ + m]);
        Aa2[j] = fminf(fmaxf(a, -10.f), -1e-6f) * LOG2E;
    }
    const float Dm = Dskip[m];
    __syncthreads();

    for (int s = 0; s < CH; ++s) {
        float dtv = ldsDt[s * 64 + ml];
        float uv  = ldsU [s * 64 + ml];
        float du  = dtv * uv;
        float4 bv = *reinterpret_cast<const float4*>(&ldsB[s * 16 + n0]);
        float4 cv = *reinterpret_cast<const float4*>(&ldsC[s * 16 + n0]);
        float bb[4] = {bv.x, bv.y, bv.z, bv.w};
        float cc[4] = {cv.x, cv.y, cv.z, cv.w};
        float y = 0.f;
#pragma unroll
        for (int j = 0; j < 4; ++j) {
            float ea = exp2f(dtv * Aa2[j]);
            h[j] = fmaf(ea, h[j], g[j] * (du * bb[j]));
            g[j] *= ea;
            y = fmaf(h[j], cc[j], y);
        }
        y += __shfl_xor(y, 16, 64);
        y += __shfl_xor(y, 32, 64);
        if (ng == 0) {
            float o = y + uv * Dm;
            o = fminf(fmaxf(o, -10000.f), 10000.f);
            out[((size_t)(b * S_ + s0 + s)) * M_ + m] = o;
        }
    }
}

extern "C" void kernel_launch(void* const* d_in, const int* in_sizes, int n_in,
                              void* d_out, int out_size, void* d_ws, size_t ws_size,
                              hipStream_t stream) {
    const float* u     = (const float*)d_in[0];
    const float* delta = (const float*)d_in[1];
    const float* Wdt   = (const float*)d_in[2];
    const float* bdt   = (const float*)d_in[3];
    const float* A_log = (const float*)d_in[4];
    const float* Dski  = (const float*)d_in[5];
    const float* Bw    = (const float*)d_in[6];
    const float* Cw    = (const float*)d_in[7];
    float* out = (float*)d_out;
    float* ws  = (float*)d_ws;

    float* dt  = ws + DT_OFF;
    float* Agg = ws + AGG_OFF;
    float* BwT = ws + BWT_OFF;
    float* CwT = ws + CWT_OFF;
    float* pB  = ws + PB_OFF;
    float* pC  = ws + PC_OFF;

    k_dt<<<dim3(4, 512), 256, 0, stream>>>(delta, Wdt, bdt, Bw, Cw, dt, BwT, CwT);
    k_bc_partial<<<dim3(256, 2), 256, 0, stream>>>(u, BwT, CwT, pB, pC);
    k_pass1<<<dim3(16, NC, B_), 256, 0, stream>>>(dt, u, pB, A_log, Agg);
    k_pass3<<<dim3(16, NC, B_), 256, 0, stream>>>(dt, u, pB, pC, A_log, Dski, Agg, out);
}

// Round 13
// 117.622 us; speedup vs baseline: 1.3784x; 1.0006x over previous
//
#include <hip/hip_runtime.h>
#include <math.h>

#define B_ 2
#define S_ 2048
#define M_ 1024
#define R_ 64
#define N_ 16
#define NC 32          // s-chunks
#define CH 64          // S_/NC
#define LOG2E 1.44269504088896f

// ws float offsets
#define DT_OFF  0                    // 4,194,304
#define AGG_OFF 4194304              // 2,097,152: [b*16+mt][c][tid][8]
#define BWT_OFF 6291456              // 16,384
#define CWT_OFF 6307840              // 16,384
#define PB_OFF  6324224              // 131,072 (2 k-split partials, B)
#define PC_OFF  6455296              // 131,072 (C)
// total 6,586,368 floats = 26.3 MiB

// ============================================================================
// dt = clip(softplus(delta @ Wdt^T + bdt), 1e-6, 10); grid (4, 512) x 256.
// Embeds the Bw/Cw transpose (8 elements per block; consumed by NEXT kernel).
// R4-exact form: W row resident in 64 VGPRs, standalone kernel -> no spill.
// ============================================================================
__global__ __launch_bounds__(256) void k_dt(const float* __restrict__ delta,
                                            const float* __restrict__ Wdt,
                                            const float* __restrict__ bdt,
                                            const float* __restrict__ Bw,
                                            const float* __restrict__ Cw,
                                            float* __restrict__ dt,
                                            float* __restrict__ BwT,
                                            float* __restrict__ CwT) {
    int bid = blockIdx.y * 4 + blockIdx.x;             // 0..2047
    if (threadIdx.x < 8) {
        int idx = bid * 8 + threadIdx.x;               // 0..16383
        int mt = idx >> 4, nt = idx & 15;
        BwT[idx] = Bw[nt * M_ + mt];
        CwT[idx] = Cw[nt * M_ + mt];
    }
    int m    = blockIdx.x * 256 + threadIdx.x;         // 0..1023
    int row0 = blockIdx.y * 8;                         // bs base
    float w[R_];
    const float4* W4 = reinterpret_cast<const float4*>(Wdt + (size_t)m * R_);
#pragma unroll
    for (int i = 0; i < R_ / 4; ++i) {
        float4 v = W4[i];
        w[4*i] = v.x; w[4*i+1] = v.y; w[4*i+2] = v.z; w[4*i+3] = v.w;
    }
    float bias = bdt[m];
#pragma unroll 1
    for (int r = 0; r < 8; ++r) {
        int bs = row0 + r;
        const float* dr = delta + (size_t)bs * R_;     // wave-uniform -> s_load
        float acc = bias;
#pragma unroll
        for (int k = 0; k < R_; ++k) acc = fmaf(dr[k], w[k], acc);
        float sp = fmaxf(acc, 0.f) + log1pf(expf(-fabsf(acc)));
        sp = fminf(fmaxf(sp, 1e-6f), 10.0f);
        dt[(size_t)bs * M_ + m] = sp;
    }
}

// ============================================================================
// B/C projection, 2-way K-split partials; grid (256 row-groups, 2 k-splits).
// R4-exact form: coalesced via BwT/CwT[k][n].
// ============================================================================
__global__ __launch_bounds__(256) void k_bc_partial(const float* __restrict__ u,
                                                    const float* __restrict__ BwT,
                                                    const float* __restrict__ CwT,
                                                    float* __restrict__ pB,
                                                    float* __restrict__ pC) {
    __shared__ float uLds[16 * 516];                   // padded: stride 516
    int r0 = blockIdx.x * 16;
    int k0 = blockIdx.y * 512;
    for (int i = threadIdx.x; i < 2048; i += 256) {
        int r = i >> 7, kq = i & 127;
        float4 v = *reinterpret_cast<const float4*>(&u[(size_t)(r0 + r) * M_ + k0 + kq * 4]);
        *reinterpret_cast<float4*>(&uLds[r * 516 + kq * 4]) = v;
    }
    __syncthreads();
    int r = threadIdx.x >> 4, n = threadIdx.x & 15;
    const float4* u4 = reinterpret_cast<const float4*>(uLds + r * 516);
    float accB = 0.f, accC = 0.f;
#pragma unroll 4
    for (int k4 = 0; k4 < 128; ++k4) {
        float4 uv = u4[k4];
        int kb = k0 + k4 * 4;
        accB = fmaf(uv.x, BwT[(kb+0)*16 + n], accB);
        accB = fmaf(uv.y, BwT[(kb+1)*16 + n], accB);
        accB = fmaf(uv.z, BwT[(kb+2)*16 + n], accB);
        accB = fmaf(uv.w, BwT[(kb+3)*16 + n], accB);
        accC = fmaf(uv.x, CwT[(kb+0)*16 + n], accC);
        accC = fmaf(uv.y, CwT[(kb+1)*16 + n], accC);
        accC = fmaf(uv.z, CwT[(kb+2)*16 + n], accC);
        accC = fmaf(uv.w, CwT[(kb+3)*16 + n], accC);
    }
    size_t o = (size_t)blockIdx.y * 65536 + (size_t)(r0 + r) * 16 + n;
    pB[o] = accB;
    pC[o] = accC;
}

// ============================================================================
// pass1: per-chunk (g = prod e^a, h) from (1,0); grid (16, NC, B_), 256 thr,
// 4 n/thread, CH=64. Agg layout [chain=(b*16+mt)][c][tid][8] -> fold reads
// are 2KB-contiguous per wave per chunk. (R11-exact.)
// ============================================================================
__global__ __launch_bounds__(256) void k_pass1(const float* __restrict__ dt,
                                               const float* __restrict__ u,
                                               const float* __restrict__ pB,
                                               const float* __restrict__ A_log,
                                               float* __restrict__ Agg) {
    __shared__ float ldsDt[CH * 64], ldsU[CH * 64], ldsB[CH * 16];
    const int m0 = blockIdx.x * 64, c = blockIdx.y, b = blockIdx.z;
    const int s0 = c * CH;
    const int tid = threadIdx.x;
    for (int i = tid; i < 1024; i += 256) {            // 64 rows x 16 float4
        int s = i >> 4, mq = (i & 15) * 4;
        size_t off = ((size_t)(b * S_ + s0 + s)) * M_ + m0 + mq;
        *reinterpret_cast<float4*>(&ldsDt[s * 64 + mq]) = *reinterpret_cast<const float4*>(&dt[off]);
        *reinterpret_cast<float4*>(&ldsU [s * 64 + mq]) = *reinterpret_cast<const float4*>(&u[off]);
    }
    {
        size_t base = (size_t)(b * S_ + s0) * N_;
        for (int i = tid; i < CH * 16; i += 256)
            ldsB[i] = pB[base + i] + pB[65536 + base + i];
    }
    __syncthreads();
    const int lane = tid & 63, wave = tid >> 6;
    const int ml = wave * 16 + (lane & 15);
    const int m  = m0 + ml;
    const int n0 = (lane >> 4) * 4;
    float Aa2[4], h[4] = {0,0,0,0}, g[4] = {1.f,1.f,1.f,1.f};
#pragma unroll
    for (int j = 0; j < 4; ++j) {
        float a = -expf(A_log[(size_t)(n0 + j) * M_ + m]);
        Aa2[j] = fminf(fmaxf(a, -10.f), -1e-6f) * LOG2E;
    }
    for (int s = 0; s < CH; ++s) {
        float dtv = ldsDt[s * 64 + ml];
        float uv  = ldsU [s * 64 + ml];
        float du  = dtv * uv;
        float4 bv = *reinterpret_cast<const float4*>(&ldsB[s * 16 + n0]);
        float bb[4] = {bv.x, bv.y, bv.z, bv.w};
#pragma unroll
        for (int j = 0; j < 4; ++j) {
            float ea = exp2f(dtv * Aa2[j]);
            h[j] = fmaf(ea, h[j], g[j] * (du * bb[j]));
            g[j] *= ea;
        }
    }
    float* dst = Agg + ((size_t)(b * 16 + blockIdx.x) * NC + c) * 2048 + tid * 8;
    *reinterpret_cast<float4*>(dst)     = make_float4(g[0], h[0], g[1], h[1]);
    *reinterpret_cast<float4*>(dst + 4) = make_float4(g[2], h[2], g[3], h[3]);
}

// ============================================================================
// pass3: fold predecessor chunk aggs (<=31, 4-batched, contiguous layout,
// fixed ascending order), then recurrence + y + out. grid (16, NC, B_).
// (R11-exact.)
// ============================================================================
__global__ __launch_bounds__(256) void k_pass3(const float* __restrict__ dt,
                                               const float* __restrict__ u,
                                               const float* __restrict__ pB,
                                               const float* __restrict__ pC,
                                               const float* __restrict__ A_log,
                                               const float* __restrict__ Dskip,
                                               const float* __restrict__ Agg,
                                               float* __restrict__ out) {
    __shared__ float ldsDt[CH * 64], ldsU[CH * 64], ldsB[CH * 16], ldsC[CH * 16];
    const int m0 = blockIdx.x * 64, c = blockIdx.y, b = blockIdx.z;
    const int s0 = c * CH;
    const int tid = threadIdx.x;
    for (int i = tid; i < 1024; i += 256) {
        int s = i >> 4, mq = (i & 15) * 4;
        size_t off = ((size_t)(b * S_ + s0 + s)) * M_ + m0 + mq;
        *reinterpret_cast<float4*>(&ldsDt[s * 64 + mq]) = *reinterpret_cast<const float4*>(&dt[off]);
        *reinterpret_cast<float4*>(&ldsU [s * 64 + mq]) = *reinterpret_cast<const float4*>(&u[off]);
    }
    {
        size_t base = (size_t)(b * S_ + s0) * N_;
        for (int i = tid; i < CH * 16; i += 256) {
            ldsB[i] = pB[base + i] + pB[65536 + base + i];
            ldsC[i] = pC[base + i] + pC[65536 + base + i];
        }
    }
    const int lane = tid & 63, wave = tid >> 6;
    const int ml = wave * 16 + (lane & 15);
    const int m  = m0 + ml;
    const int ng = lane >> 4, n0 = ng * 4;

    // ---- exclusive fold over chunks 0..c-1 (fixed order, contiguous reads) ----
    float g[4] = {1.f,1.f,1.f,1.f}, h[4] = {0.f,0.f,0.f,0.f};
    {
        const float* aggB = Agg + (size_t)(b * 16 + blockIdx.x) * NC * 2048 + tid * 8;
        int cp = 0;
        for (; cp + 4 <= c; cp += 4) {
            float4 q[8];
#pragma unroll
            for (int t = 0; t < 4; ++t) {
                q[2*t]   = *reinterpret_cast<const float4*>(aggB + (size_t)(cp + t) * 2048);
                q[2*t+1] = *reinterpret_cast<const float4*>(aggB + (size_t)(cp + t) * 2048 + 4);
            }
#pragma unroll
            for (int t = 0; t < 4; ++t) {
                float4 a0 = q[2*t], a1 = q[2*t+1];
                h[0] = fmaf(a0.x, h[0], g[0] * a0.y); g[0] *= a0.x;
                h[1] = fmaf(a0.z, h[1], g[1] * a0.w); g[1] *= a0.z;
                h[2] = fmaf(a1.x, h[2], g[2] * a1.y); g[2] *= a1.x;
                h[3] = fmaf(a1.z, h[3], g[3] * a1.w); g[3] *= a1.z;
            }
        }
        for (; cp < c; ++cp) {
            float4 a0 = *reinterpret_cast<const float4*>(aggB + (size_t)cp * 2048);
            float4 a1 = *reinterpret_cast<const float4*>(aggB + (size_t)cp * 2048 + 4);
            h[0] = fmaf(a0.x, h[0], g[0] * a0.y); g[0] *= a0.x;
            h[1] = fmaf(a0.z, h[1], g[1] * a0.w); g[1] *= a0.z;
            h[2] = fmaf(a1.x, h[2], g[2] * a1.y); g[2] *= a1.x;
            h[3] = fmaf(a1.z, h[3], g[3] * a1.w); g[3] *= a1.z;
        }
    }
    float Aa2[4];
#pragma unroll
    for (int j = 0; j < 4; ++j) {
        float a = -expf(A_log[(size_t)(n0 + j) * M_ + m]);
        Aa2[j] = fminf(fmaxf(a, -10.f), -1e-6f) * LOG2E;
    }
    const float Dm = Dskip[m];
    __syncthreads();

    for (int s = 0; s < CH; ++s) {
        float dtv = ldsDt[s * 64 + ml];
        float uv  = ldsU [s * 64 + ml];
        float du  = dtv * uv;
        float4 bv = *reinterpret_cast<const float4*>(&ldsB[s * 16 + n0]);
        float4 cv = *reinterpret_cast<const float4*>(&ldsC[s * 16 + n0]);
        float bb[4] = {bv.x, bv.y, bv.z, bv.w};
        float cc[4] = {cv.x, cv.y, cv.z, cv.w};
        float y = 0.f;
#pragma unroll
        for (int j = 0; j < 4; ++j) {
            float ea = exp2f(dtv * Aa2[j]);
            h[j] = fmaf(ea, h[j], g[j] * (du * bb[j]));
            g[j] *= ea;
            y = fmaf(h[j], cc[j], y);
        }
        y += __shfl_xor(y, 16, 64);
        y += __shfl_xor(y, 32, 64);
        if (ng == 0) {
            float o = y + uv * Dm;
            o = fminf(fmaxf(o, -10000.f), 10000.f);
            out[((size_t)(b * S_ + s0 + s)) * M_ + m] = o;
        }
    }
}

extern "C" void kernel_launch(void* const* d_in, const int* in_sizes, int n_in,
                              void* d_out, int out_size, void* d_ws, size_t ws_size,
                              hipStream_t stream) {
    const float* u     = (const float*)d_in[0];
    const float* delta = (const float*)d_in[1];
    const float* Wdt   = (const float*)d_in[2];
    const float* bdt   = (const float*)d_in[3];
    const float* A_log = (const float*)d_in[4];
    const float* Dski  = (const float*)d_in[5];
    const float* Bw    = (const float*)d_in[6];
    const float* Cw    = (const float*)d_in[7];
    float* out = (float*)d_out;
    float* ws  = (float*)d_ws;

    float* dt  = ws + DT_OFF;
    float* Agg = ws + AGG_OFF;
    float* BwT = ws + BWT_OFF;
    float* CwT = ws + CWT_OFF;
    float* pB  = ws + PB_OFF;
    float* pC  = ws + PC_OFF;

    k_dt<<<dim3(4, 512), 256, 0, stream>>>(delta, Wdt, bdt, Bw, Cw, dt, BwT, CwT);
    k_bc_partial<<<dim3(256, 2), 256, 0, stream>>>(u, BwT, CwT, pB, pC);
    k_pass1<<<dim3(16, NC, B_), 256, 0, stream>>>(dt, u, pB, A_log, Agg);
    k_pass3<<<dim3(16, NC, B_), 256, 0, stream>>>(dt, u, pB, pC, A_log, Dski, Agg, out);
}